// Round 1
// baseline (459.579 us; speedup 1.0000x reference)
//
#include <hip/hip_runtime.h>

#define KH 5
#define KW 5
#define HH 256
#define WW 256
#define HO 252
#define WO 252
#define NB 16
#define NO 64
#define TL 16           // l-positions per block
#define XC (TL + KW - 1) // 20 columns of x staged
#define DSTRIDE 1025    // 1024 + 1 pad (breaks p-stride bank conflicts)

__global__ __launch_bounds__(512, 4)
void rbf_conv2d_kernel(const float* __restrict__ x, const float* __restrict__ w,
                       float* __restrict__ out) {
    __shared__ float xs[NB][KH][XC];      // 1600 floats
    __shared__ float wn[NO];              // 64
    __shared__ float dist[TL * DSTRIDE];  // 16400 floats (65.6 KB)
    __shared__ float partial[32][16];     // part x p
    __shared__ float meanv[TL];
    __shared__ float cinv[TL];            // -0.5 / var

    const int t  = threadIdx.x;
    const int k  = blockIdx.y;
    const int l0 = blockIdx.x * TL;

    // ---- stage x tile: 16 batches x 5 rows x 20 cols (clamp cols at edge) ----
    for (int idx = t; idx < NB * KH * XC; idx += 512) {
        int b   = idx / (KH * XC);
        int rem = idx % (KH * XC);
        int r   = rem / XC;
        int c   = rem % XC;
        int col = l0 + c;
        if (col > WW - 1) col = WW - 1;   // tail-block clamp (outputs guarded)
        xs[b][r][c] = x[(b * HH + (k + r)) * WW + col];
    }
    // ---- weight norms ----
    if (t < NO) {
        float s = 0.f;
        #pragma unroll
        for (int i = 0; i < 25; ++i) { float v = w[t * 25 + i]; s = fmaf(v, v, s); }
        wn[t] = s;
    }
    __syncthreads();

    // ---- distance phase: thread = (p = l-offset, b, o-group), 32 o's each ----
    {
        const int p  = t & 15;
        const int b  = (t >> 4) & 15;
        const int og = t >> 8;            // 0 or 1
        float pr[25];
        float pn = 0.f;
        #pragma unroll
        for (int r = 0; r < KH; ++r)
            #pragma unroll
            for (int c = 0; c < KW; ++c) {
                float v = xs[b][r][p + c];
                pr[r * KW + c] = v;
                pn = fmaf(v, v, pn);
            }
        float* drow = &dist[p * DSTRIDE + b * 64];
        const int obase = og * 32;
        #pragma unroll 4
        for (int oi = 0; oi < 32; ++oi) {
            const int o = obase + oi;
            const float* __restrict__ wrow = w + o * 25;  // wave-uniform -> s_load
            float a0 = 0.f, a1 = 0.f, a2 = 0.f, a3 = 0.f;
            #pragma unroll
            for (int i = 0; i < 24; i += 4) {
                a0 = fmaf(pr[i + 0], wrow[i + 0], a0);
                a1 = fmaf(pr[i + 1], wrow[i + 1], a1);
                a2 = fmaf(pr[i + 2], wrow[i + 2], a2);
                a3 = fmaf(pr[i + 3], wrow[i + 3], a3);
            }
            a0 = fmaf(pr[24], wrow[24], a0);
            float cross = (a0 + a1) + (a2 + a3);
            float d2 = pn + wn[o] - 2.0f * cross;
            d2 = fmaxf(d2, 1e-12f);
            drow[o] = sqrtf(d2);
        }
    }
    __syncthreads();

    // ---- mean over the 1024 (b,o) per position p ----
    {
        const int p = t & 15;
        const int part = t >> 4;          // 0..31
        const float* drow = &dist[p * DSTRIDE + part * 32];
        float s = 0.f;
        #pragma unroll
        for (int j = 0; j < 32; ++j) s += drow[j];
        partial[part][p] = s;
    }
    __syncthreads();
    if (t < TL) {
        float s = 0.f;
        #pragma unroll
        for (int part = 0; part < 32; ++part) s += partial[part][t];
        meanv[t] = s * (1.0f / 1024.0f);
    }
    __syncthreads();

    // ---- var (ddof=1), two-pass like the reference ----
    {
        const int p = t & 15;
        const int part = t >> 4;
        const float m = meanv[p];
        const float* drow = &dist[p * DSTRIDE + part * 32];
        float s = 0.f;
        #pragma unroll
        for (int j = 0; j < 32; ++j) { float d = drow[j] - m; s = fmaf(d, d, s); }
        partial[part][p] = s;
    }
    __syncthreads();
    if (t < TL) {
        float s = 0.f;
        #pragma unroll
        for (int part = 0; part < 32; ++part) s += partial[part][t];
        float var = s * (1.0f / 1023.0f);
        cinv[t] = -0.5f / var;
    }
    __syncthreads();

    // ---- output: lanes cover 16 consecutive l -> 64B-coalesced stores ----
    {
        const int li = t & 15;
        const int l  = l0 + li;
        const bool ok = (l < WO);
        const float c = cinv[li];
        const float* drow = &dist[li * DSTRIDE];
        #pragma unroll 4
        for (int j = 0; j < 32; ++j) {
            int bo = j * 32 + (t >> 4);   // plane index b*64+o
            float d = drow[bo];
            float v = __expf(d * d * c);
            if (ok) out[(bo * HO + k) * WO + l] = v;
        }
    }
}

extern "C" void kernel_launch(void* const* d_in, const int* in_sizes, int n_in,
                              void* d_out, int out_size, void* d_ws, size_t ws_size,
                              hipStream_t stream) {
    const float* x = (const float*)d_in[0];
    const float* w = (const float*)d_in[1];
    float* out = (float*)d_out;
    dim3 grid((WO + TL - 1) / TL, HO);   // (16, 252)
    rbf_conv2d_kernel<<<grid, 512, 0, stream>>>(x, w, out);
}

// Round 2
// 330.235 us; speedup vs baseline: 1.3917x; 1.3917x over previous
//
#include <hip/hip_runtime.h>

typedef float v2f __attribute__((ext_vector_type(2)));

#define KH 5
#define KW 5
#define HH 256
#define WW 256
#define HO 252
#define WO 252
#define NB 16
#define NO 64
#define TL 16
#define XC (TL + KW - 1)
#define PLANE (HO * WO)

// Thread map: p = t&15 (l offset), b = (t>>4)&15 (batch), og = t>>8 (o half).
// Each thread computes 32 distances (its b, its l, o in [og*32, og*32+32)),
// held in registers as 16 v2f pairs. Weights are read via wave-uniform
// (readfirstlane'd) addresses -> s_load, feeding v_pk_fma_f32.
// Output tiles are shifted by a0=(4k)&15 so every 16-lane store is one
// aligned 64B line (row byte offset within plane is 48k mod 64).
__global__ __launch_bounds__(512, 4)
void rbf_conv2d_kernel(const float* __restrict__ x, const float* __restrict__ w,
                       float* __restrict__ out) {
    __shared__ float xs[NB][KH][XC];      // 6.4 KB
    __shared__ float wn[NO];
    __shared__ float partial[32][TL];     // 2 KB
    __shared__ float meanv[TL];
    __shared__ float cinv[TL];            // -0.5*log2(e)/var

    const int t  = threadIdx.x;
    const int k  = blockIdx.y;
    const int a0 = (4 * k) & 15;                  // alignment shift for this row
    const int l0 = a0 - TL + (blockIdx.x << 4);
    if (l0 >= WO || l0 + TL <= 0) return;         // uniform early-out, pre-barrier

    // ---- stage x tile (cols clamped; clamped cols only feed masked lanes) ----
    for (int idx = t; idx < NB * KH * XC; idx += 512) {
        int b   = idx / (KH * XC);
        int rem = idx % (KH * XC);
        int r   = rem / XC;
        int c   = rem % XC;
        int col = l0 + c;
        col = col < 0 ? 0 : (col > WW - 1 ? WW - 1 : col);
        xs[b][r][c] = x[(b * HH + k + r) * WW + col];
    }
    if (t < NO) {
        float s = 0.f;
        #pragma unroll
        for (int i = 0; i < 25; ++i) { float v = w[t * 25 + i]; s = fmaf(v, v, s); }
        wn[t] = s;
    }
    __syncthreads();

    const int p = t & 15;
    const int b = (t >> 4) & 15;
    // force SGPR so weight addresses scalarize -> s_load_dwordx8
    const int obase = __builtin_amdgcn_readfirstlane((t >> 8) << 5);

    // ---- patch into registers, packed as v2f pairs for v_pk_fma_f32 ----
    float pr[25];
    float pn = 0.f;
    #pragma unroll
    for (int r = 0; r < KH; ++r)
        #pragma unroll
        for (int c = 0; c < KW; ++c) {
            float v = xs[b][r][p + c];
            pr[r * KW + c] = v;
            pn = fmaf(v, v, pn);
        }
    v2f prv[12];
    #pragma unroll
    for (int i = 0; i < 12; ++i) { prv[i].x = pr[2 * i]; prv[i].y = pr[2 * i + 1]; }
    const float pr24 = pr[24];

    // ---- 32 distances in registers ----
    v2f dv[16];
    #pragma unroll
    for (int j = 0; j < 16; ++j) {
        float cr0, cr1;
        {
            const float* __restrict__ wr = w + (obase + 2 * j) * 25;
            v2f acc = {0.f, 0.f};
            #pragma unroll
            for (int i = 0; i < 12; ++i) {
                v2f wv; wv.x = wr[2 * i]; wv.y = wr[2 * i + 1];
                acc = __builtin_elementwise_fma(prv[i], wv, acc);
            }
            cr0 = acc.x + acc.y + pr24 * wr[24];
        }
        {
            const float* __restrict__ wr = w + (obase + 2 * j + 1) * 25;
            v2f acc = {0.f, 0.f};
            #pragma unroll
            for (int i = 0; i < 12; ++i) {
                v2f wv; wv.x = wr[2 * i]; wv.y = wr[2 * i + 1];
                acc = __builtin_elementwise_fma(prv[i], wv, acc);
            }
            cr1 = acc.x + acc.y + pr24 * wr[24];
        }
        float d20 = fmaxf(fmaf(-2.f, cr0, pn + wn[obase + 2 * j]),     1e-12f);
        float d21 = fmaxf(fmaf(-2.f, cr1, pn + wn[obase + 2 * j + 1]), 1e-12f);
        dv[j].x = __builtin_amdgcn_sqrtf(d20);
        dv[j].y = __builtin_amdgcn_sqrtf(d21);
    }

    // ---- mean over 1024 per position p (register partials + tiny LDS) ----
    {
        float s = 0.f;
        #pragma unroll
        for (int j = 0; j < 16; ++j) s += dv[j].x + dv[j].y;
        partial[t >> 4][p] = s;
    }
    __syncthreads();
    if (t < TL) {
        float m = 0.f;
        #pragma unroll
        for (int q = 0; q < 32; ++q) m += partial[q][t];
        meanv[t] = m * (1.0f / 1024.0f);
    }
    __syncthreads();
    {
        const float m = meanv[p];
        float vs = 0.f;
        #pragma unroll
        for (int j = 0; j < 16; ++j) {
            float d0 = dv[j].x - m, d1 = dv[j].y - m;
            vs = fmaf(d0, d0, fmaf(d1, d1, vs));
        }
        partial[t >> 4][p] = vs;
    }
    __syncthreads();
    if (t < TL) {
        float v = 0.f;
        #pragma unroll
        for (int q = 0; q < 32; ++q) v += partial[q][t];
        v *= (1.0f / 1023.0f);
        // exp(-0.5 d^2/var) = exp2(d^2 * (-0.5*log2e/var))
        cinv[t] = -0.72134752044448170368f / v;
    }
    __syncthreads();

    // ---- epilogue: aligned full-line stores ----
    {
        const int l = l0 + p;
        const bool ok = (l >= 0) && (l < WO);
        const float c = cinv[p];
        v2f cv; cv.x = c; cv.y = c;
        const int base = ((b * NO + obase) * HO + k) * WO + l;
        #pragma unroll
        for (int j = 0; j < 16; ++j) {
            v2f tt = dv[j] * dv[j];
            tt = tt * cv;
            float e0 = exp2f(tt.x);
            float e1 = exp2f(tt.y);
            if (ok) {
                out[base + (2 * j) * PLANE]     = e0;
                out[base + (2 * j + 1) * PLANE] = e1;
            }
        }
    }
}

extern "C" void kernel_launch(void* const* d_in, const int* in_sizes, int n_in,
                              void* d_out, int out_size, void* d_ws, size_t ws_size,
                              hipStream_t stream) {
    const float* x = (const float*)d_in[0];
    const float* w = (const float*)d_in[1];
    float* out = (float*)d_out;
    dim3 grid(17, HO);   // 17 shifted l-tiles x 252 rows
    rbf_conv2d_kernel<<<grid, 512, 0, stream>>>(x, w, out);
}